// Round 3
// baseline (556.210 us; speedup 1.0000x reference)
//
#include <hip/hip_runtime.h>
#include <math.h>

namespace {

constexpr int T_ = 1024;
constexpr int HKV_ = 8;
constexpr int M_ = 8;
constexpr int D_ = 64;
constexpr int WIN_ = 128;
constexpr float SCALE_ = 0.125f;   // 1/sqrt(64)

constexpr int IB_ = 8;             // query rows per block (1 per wave)
constexpr int NKEY_ = 136;         // staged keys: [i0-127, i0+8]
constexpr int NTHREADS_ = 512;

using f4 = __attribute__((ext_vector_type(4))) float;

// Writes ONLY the nonzero band [jlo, i] of each softmax row, directly from
// the registers that computed the probabilities. The rest of the output is
// zero-filled by hipMemsetAsync before this kernel runs (stream-ordered).
__global__ void attn_band(const float* __restrict__ qg,
                          const float* __restrict__ kg,
                          const float* __restrict__ sinks,
                          float* __restrict__ outg)
{
    __shared__ float k_lds[NKEY_ * D_];     // XOR-swizzled key rows
    __shared__ float q_lds[IB_][M_ * D_];   // per-wave q row (broadcast reads)

    const int tid  = threadIdx.x;
    const int wave = tid >> 6;
    const int lane = tid & 63;
    const int h    = blockIdx.x / (T_ / IB_);
    const int i0   = (blockIdx.x % (T_ / IB_)) * IB_;
    const int base = i0 - (WIN_ - 1);       // global j of staged key r=0

    // ---- stage K window into LDS (swizzled: c4 ^= ((r>>1)&7)<<2) ----
    for (int f = tid; f < NKEY_ * (D_ / 4); f += NTHREADS_) {
        const int r  = f >> 4;
        const int c4 = (f & 15) << 2;
        const int j  = base + r;
        f4 v = {0.f, 0.f, 0.f, 0.f};
        if ((unsigned)j < (unsigned)T_)
            v = *reinterpret_cast<const f4*>(kg + ((size_t)j * HKV_ + h) * D_ + c4);
        const int sw = c4 ^ (((r >> 1) & 7) << 2);
        *reinterpret_cast<f4*>(&k_lds[r * D_ + sw]) = v;
    }
    // ---- stage this wave's q row (512 floats) ----
    {
        const int i = i0 + wave;
        const float* qp = qg + ((size_t)i * HKV_ + h) * (M_ * D_);
        const int off = lane * 4;
        *reinterpret_cast<f4*>(&q_lds[wave][off]) =
            *reinterpret_cast<const f4*>(qp + off);
        *reinterpret_cast<f4*>(&q_lds[wave][off + 256]) =
            *reinterpret_cast<const f4*>(qp + off + 256);
    }
    __syncthreads();

    const int i   = i0 + wave;
    const int jlo = (i >= WIN_ - 1) ? (i - (WIN_ - 1)) : 0;
    const int cnt = i - jlo + 1;            // 1..128 valid keys
    const int rlo = jlo - base;             // rel idx of first valid key

    const int idx0 = 2 * lane;
    const int idx1 = idx0 + 1;
    const bool v0 = idx0 < cnt;
    const bool v1 = idx1 < cnt;
    int r0 = rlo + idx0; if (r0 > NKEY_ - 1) r0 = NKEY_ - 1;
    int r1 = rlo + idx1; if (r1 > NKEY_ - 1) r1 = NKEY_ - 1;

    float acc0[M_], acc1[M_];
    #pragma unroll
    for (int m = 0; m < M_; ++m) { acc0[m] = 0.f; acc1[m] = 0.f; }

    const float* k0p = &k_lds[r0 * D_];
    const float* k1p = &k_lds[r1 * D_];
    const int sw0 = ((r0 >> 1) & 7) << 2;
    const int sw1 = ((r1 >> 1) & 7) << 2;

    #pragma unroll
    for (int c = 0; c < 16; ++c) {
        const int c4 = c << 2;
        const f4 kv0 = *reinterpret_cast<const f4*>(k0p + (c4 ^ sw0));
        const f4 kv1 = *reinterpret_cast<const f4*>(k1p + (c4 ^ sw1));
        #pragma unroll
        for (int m = 0; m < M_; ++m) {
            const f4 qv = *reinterpret_cast<const f4*>(&q_lds[wave][m * D_ + c4]);
            acc0[m] = fmaf(qv.x, kv0.x, acc0[m]);
            acc0[m] = fmaf(qv.y, kv0.y, acc0[m]);
            acc0[m] = fmaf(qv.z, kv0.z, acc0[m]);
            acc0[m] = fmaf(qv.w, kv0.w, acc0[m]);
            acc1[m] = fmaf(qv.x, kv1.x, acc1[m]);
            acc1[m] = fmaf(qv.y, kv1.y, acc1[m]);
            acc1[m] = fmaf(qv.z, kv1.z, acc1[m]);
            acc1[m] = fmaf(qv.w, kv1.w, acc1[m]);
        }
    }

    // ---- per-m softmax (with sink) + register-direct band store ----
    #pragma unroll
    for (int m = 0; m < M_; ++m) {
        float l0 = v0 ? acc0[m] * SCALE_ : -INFINITY;
        float l1 = v1 ? acc1[m] * SCALE_ : -INFINITY;
        float mx = fmaxf(l0, l1);
        #pragma unroll
        for (int s = 1; s < 64; s <<= 1)
            mx = fmaxf(mx, __shfl_xor(mx, s, 64));
        const float slog = sinks[h * M_ + m];
        mx = fmaxf(mx, slog);
        float p0 = __expf(l0 - mx);            // exp(-inf)=0 for masked keys
        float p1 = __expf(l1 - mx);
        float sum = p0 + p1;
        #pragma unroll
        for (int s = 1; s < 64; s <<= 1)
            sum += __shfl_xor(sum, s, 64);
        const float inv = 1.0f / (sum + __expf(slog - mx));
        p0 *= inv;
        p1 *= inv;

        // Band [jlo, jlo+cnt) is contiguous; lane l owns floats jlo+2l, jlo+2l+1.
        // Plain dword stores: wave-contiguous, L2 combines into full lines.
        float* orow = outg + (((size_t)(h * M_ + m) * T_ + i) * T_) + jlo;
        if (v0) orow[idx0] = p0;
        if (v1) orow[idx1] = p1;
    }
}

} // namespace

extern "C" void kernel_launch(void* const* d_in, const int* in_sizes, int n_in,
                              void* d_out, int out_size, void* d_ws, size_t ws_size,
                              hipStream_t stream) {
    const float* q     = (const float*)d_in[0];
    const float* k     = (const float*)d_in[1];
    const float* sinks = (const float*)d_in[2];
    float* out         = (float*)d_out;

    // Phase 1: zero the whole output (87.5% of it stays zero). Driver memset
    // is full-BW and immune to partial-line store pathologies.
    hipMemsetAsync(out, 0, (size_t)out_size * sizeof(float), stream);

    // Phase 2: compute softmax band and scatter only the nonzero values.
    dim3 grid(HKV_ * (T_ / IB_));   // 8 heads * 128 i-blocks = 1024 blocks
    attn_band<<<grid, NTHREADS_, 0, stream>>>(q, k, sinks, out);
}

// Round 4
// 56.349 us; speedup vs baseline: 9.8708x; 9.8708x over previous
//
#include <hip/hip_runtime.h>
#include <math.h>

namespace {

constexpr int T_ = 1024;
constexpr int HKV_ = 8;
constexpr int M_ = 8;
constexpr int D_ = 64;
constexpr int WIN_ = 128;
constexpr float SCALE_ = 0.125f;   // 1/sqrt(64)

constexpr int IB_ = 8;             // query rows per block (1 per wave)
constexpr int NKEY_ = 136;         // staged keys: [i0-127, i0+8]
constexpr int NTHREADS_ = 512;

using f4 = __attribute__((ext_vector_type(4))) float;

__global__ void attn_qk_softmax(const float* __restrict__ qg,
                                const float* __restrict__ kg,
                                const float* __restrict__ sinks,
                                float* __restrict__ outg)
{
    __shared__ float k_lds[NKEY_ * D_];       // XOR-swizzled key rows
    __shared__ float q_lds[IB_][M_ * D_];     // per-wave q rows (broadcast reads)
    __shared__ float p_lds[IB_][2][136];      // pad-17 probs, double-buffered per m

    const int tid  = threadIdx.x;
    const int wave = tid >> 6;
    const int lane = tid & 63;
    const int h    = blockIdx.x / (T_ / IB_);
    const int i0   = (blockIdx.x % (T_ / IB_)) * IB_;
    const int base = i0 - (WIN_ - 1);         // global j of staged key r=0

    // ---- stage K window into LDS (swizzled: c4 ^= ((r>>1)&7)<<2) ----
    for (int f = tid; f < NKEY_ * (D_ / 4); f += NTHREADS_) {
        const int r  = f >> 4;
        const int c4 = (f & 15) << 2;
        const int j  = base + r;
        f4 v = {0.f, 0.f, 0.f, 0.f};
        if ((unsigned)j < (unsigned)T_)
            v = *reinterpret_cast<const f4*>(kg + ((size_t)j * HKV_ + h) * D_ + c4);
        const int sw = c4 ^ (((r >> 1) & 7) << 2);
        *reinterpret_cast<f4*>(&k_lds[r * D_ + sw]) = v;
    }
    // ---- stage this wave's q rows (512 floats) ----
    {
        const int i = i0 + wave;
        const float* qp = qg + ((size_t)i * HKV_ + h) * (M_ * D_);
        const int off = lane * 4;
        *reinterpret_cast<f4*>(&q_lds[wave][off]) =
            *reinterpret_cast<const f4*>(qp + off);
        *reinterpret_cast<f4*>(&q_lds[wave][off + 256]) =
            *reinterpret_cast<const f4*>(qp + off + 256);
    }
    __syncthreads();

    const int i   = i0 + wave;
    const int jlo = (i >= WIN_ - 1) ? (i - (WIN_ - 1)) : 0;
    const int cnt = i - jlo + 1;              // 1..128 valid keys
    const int rlo = jlo - base;               // rel idx of first valid key

    const int idx0 = 2 * lane;
    const int idx1 = idx0 + 1;
    const bool v0 = idx0 < cnt;
    const bool v1 = idx1 < cnt;
    int r0 = rlo + idx0; if (r0 > NKEY_ - 1) r0 = NKEY_ - 1;
    int r1 = rlo + idx1; if (r1 > NKEY_ - 1) r1 = NKEY_ - 1;

    float acc0[M_], acc1[M_];
    #pragma unroll
    for (int m = 0; m < M_; ++m) { acc0[m] = 0.f; acc1[m] = 0.f; }

    const float* k0p = &k_lds[r0 * D_];
    const float* k1p = &k_lds[r1 * D_];
    const int sw0 = ((r0 >> 1) & 7) << 2;
    const int sw1 = ((r1 >> 1) & 7) << 2;

    #pragma unroll
    for (int c = 0; c < 16; ++c) {
        const int c4 = c << 2;
        const f4 kv0 = *reinterpret_cast<const f4*>(k0p + (c4 ^ sw0));
        const f4 kv1 = *reinterpret_cast<const f4*>(k1p + (c4 ^ sw1));
        #pragma unroll
        for (int m = 0; m < M_; ++m) {
            const f4 qv = *reinterpret_cast<const f4*>(&q_lds[wave][m * D_ + c4]);
            acc0[m] = fmaf(qv.x, kv0.x, acc0[m]);
            acc0[m] = fmaf(qv.y, kv0.y, acc0[m]);
            acc0[m] = fmaf(qv.z, kv0.z, acc0[m]);
            acc0[m] = fmaf(qv.w, kv0.w, acc0[m]);
            acc1[m] = fmaf(qv.x, kv1.x, acc1[m]);
            acc1[m] = fmaf(qv.y, kv1.y, acc1[m]);
            acc1[m] = fmaf(qv.z, kv1.z, acc1[m]);
            acc1[m] = fmaf(qv.w, kv1.w, acc1[m]);
        }
    }

    // ---- per-m softmax (with sink) + full-row PLAIN contiguous store ----
    #pragma unroll
    for (int m = 0; m < M_; ++m) {
        float l0 = v0 ? acc0[m] * SCALE_ : -INFINITY;
        float l1 = v1 ? acc1[m] * SCALE_ : -INFINITY;
        float mx = fmaxf(l0, l1);
        #pragma unroll
        for (int s = 1; s < 64; s <<= 1)
            mx = fmaxf(mx, __shfl_xor(mx, s, 64));
        const float slog = sinks[h * M_ + m];
        mx = fmaxf(mx, slog);
        float p0 = __expf(l0 - mx);            // exp(-inf)=0 for masked keys
        float p1 = __expf(l1 - mx);
        float sum = p0 + p1;
        #pragma unroll
        for (int s = 1; s < 64; s <<= 1)
            sum += __shfl_xor(sum, s, 64);
        const float inv = 1.0f / (sum + __expf(slog - mx));
        p0 *= inv;
        p1 *= inv;

        float* pb = p_lds[wave][m & 1];        // double buffer
        pb[idx0 + (idx0 >> 4)] = p0;
        pb[idx1 + (idx1 >> 4)] = p1;
        asm volatile("s_waitcnt lgkmcnt(0)" ::: "memory");  // writes visible to wave

        // Full 4 KB row, 4 plain f4 stores per lane; each instruction covers
        // 1 KB contiguous = 8 full 128B lines sourced entirely from this wave.
        float* orow = outg + (((size_t)(h * M_ + m) * T_ + i) * T_);
        #pragma unroll
        for (int t = 0; t < 4; ++t) {
            const int j = t * 256 + lane * 4;  // float index in row
            f4 ov;
            #pragma unroll
            for (int u = 0; u < 4; ++u) {
                int idx = j + u - jlo;
                const bool in = (unsigned)idx < (unsigned)cnt;
                int ci = idx; if (ci < 0) ci = 0; if (ci > 127) ci = 127;
                const float val = pb[ci + (ci >> 4)];
                ov[u] = in ? val : 0.0f;
            }
            *reinterpret_cast<f4*>(orow + j) = ov;   // plain cached store
        }
    }
}

} // namespace

extern "C" void kernel_launch(void* const* d_in, const int* in_sizes, int n_in,
                              void* d_out, int out_size, void* d_ws, size_t ws_size,
                              hipStream_t stream) {
    const float* q     = (const float*)d_in[0];
    const float* k     = (const float*)d_in[1];
    const float* sinks = (const float*)d_in[2];
    float* out         = (float*)d_out;

    dim3 grid(HKV_ * (T_ / IB_));   // 8 heads * 128 i-blocks = 1024 blocks
    attn_qk_softmax<<<grid, NTHREADS_, 0, stream>>>(q, k, sinks, out);
}